// Round 6
// baseline (321.656 us; speedup 1.0000x reference)
//
#include <hip/hip_runtime.h>
#include <math.h>

// LSTM B=8192,T=512,IN=3,H=32,OUT=2 fp32.
// R14: 8-wave blocks, 1 unit-batch per lane -> 4 waves/SIMD.
// R13 post-mortem: idle ~25% of the 1275-cyc step; 2 waves/SIMD cannot cover
// the serial chain (barrier -> ds_read ~120 -> MFMA depth-3 ~150 -> trans
// chain ~200). At 2 unit-batches/lane the problem yields exactly 2048 waves
// = 2/SIMD; occupancy and f32x2-packing trade off directly. This round buys
// occupancy: block = 512 thr (8 waves), wave w owns units 4w..4w+3, lane
// (n,q) owns unit 4w+q of batch n (scalar gate math, 7 trans/lane/step).
// grid 512 x 512thr = 4096 waves = 4/SIMD, 2 independent blocks/CU.
// Per-SIMD issue work conserved vs R13 (12 MFMA, 28 trans wave-instr per
// SIMD-step); scalarization adds ~200 cyc but 4-way wave interleave should
// collapse the ~314-cyc idle.
// A-perm (1 chunk): A row m -> W row R(m) = 32*(m&3) + 4w + (m>>2)
//   => D row 4q+r = gate r of unit 4w+q. Zero selects, zero cross-lane.
// Unchanged: hi/lo bf16 h (3 MFMA passes, C carries exact fp32 x-preacts),
// fused triple-rcp c-update, double-buffered LDS [2][2][16][40] u16,
// 1 barrier/step, block-parity s_sleep stagger.

namespace {
constexpr int   kT      = 512;
constexpr float kL2E    = 1.44269504088896340736f;
constexpr int   kStride = 40;   // ushorts per LDS row: 32 units + 8 pad
}

typedef __bf16 bf16x8 __attribute__((ext_vector_type(8)));
typedef float  f32x4  __attribute__((ext_vector_type(4)));
typedef unsigned int u32x4 __attribute__((ext_vector_type(4)));

union Frag {
    bf16x8 v;
    unsigned short u[8];
    unsigned int   d[4];
    u32x4          q4;
};

__device__ __forceinline__ unsigned short bf_rne(float f) {
    unsigned u = __float_as_uint(f);
    u += 0x7fffu + ((u >> 16) & 1u);
    return (unsigned short)(u >> 16);
}
__device__ __forceinline__ float bf_tof(unsigned short h) {
    return __uint_as_float((unsigned)h << 16);
}
__device__ __forceinline__ float fast_exp2(float v) { return __builtin_amdgcn_exp2f(v); }
__device__ __forceinline__ float fast_rcp(float v)  { return __builtin_amdgcn_rcpf(v); }

#define MFMA16 __builtin_amdgcn_mfma_f32_16x16x32_bf16

extern "C" __global__ __launch_bounds__(512, 4)
void lstm_split8(const float* __restrict__ x,
                 const float* __restrict__ W_ih,
                 const float* __restrict__ W_hh,
                 const float* __restrict__ b_ih,
                 const float* __restrict__ b_hh,
                 const float* __restrict__ W_fc,
                 const float* __restrict__ b_fc,
                 float* __restrict__ out) {
    const int tid  = threadIdx.x;
    const int lane = tid & 63;
    const int w    = tid >> 6;          // wave id 0..7: owns units 4w..4w+3
    const int n    = lane & 15;         // batch-within-block == B/D column
    const int q    = lane >> 4;         // k-quad / D row group
    const int bid  = blockIdx.x;
    const int batch = bid * 16 + n;

    // double-buffered h planes: [buf][hi/lo][batch][unit+pad]
    __shared__ __align__(16) unsigned short lds_h[2][2][16][kStride];

    // ---- A frag (1 chunk): A row m -> W row R(m) = 32*(m&3) + 4w + (m>>2).
    // HW: A row = lane&15 (=n), k = 8q+j; D col = lane&15, row = 4q+reg.
    // => acc[r] = gate r of unit u = 4w + q.
    Frag Ah, Al;
    {
        const int   g = n & 3;
        const float s = (g == 2) ? -2.0f * kL2E : -kL2E;
        const int   R = 32 * g + 4 * w + (n >> 2);
#pragma unroll
        for (int j = 0; j < 8; ++j) {
            const float wv = W_hh[R * 32 + 8 * q + j] * s;
            const unsigned short hb = bf_rne(wv);
            Ah.u[j] = hb;
            Al.u[j] = bf_rne(wv - bf_tof(hb));
        }
    }

    // ---- x-path constants: my unit u0 = 4w+q, 4 gates ----
    const int u0 = 4 * w + q;
    float xw[4][3], xbias[4];
#pragma unroll
    for (int g = 0; g < 4; ++g) {
        const float s = (g == 2) ? -2.0f * kL2E : -kL2E;
        const int   R = 32 * g + u0;
#pragma unroll
        for (int k = 0; k < 3; ++k) xw[g][k] = W_ih[R * 3 + k] * s;
        xbias[g] = (b_ih[R] + b_hh[R]) * s;
    }

    const float* xb = x + (size_t)batch * kT * 3;

    float cst = 0.f;
    Frag Bh, Bl;
#pragma unroll
    for (int j = 0; j < 4; ++j) { Bh.d[j] = 0; Bl.d[j] = 0; }

    // prologue: xp = XP(0); xc = x(1)
    f32x4 xp;
    {
        const float a0 = xb[0], a1 = xb[1], a2 = xb[2];
#pragma unroll
        for (int g = 0; g < 4; ++g)
            xp[g] = fmaf(a0, xw[g][0],
                    fmaf(a1, xw[g][1],
                    fmaf(a2, xw[g][2], xbias[g])));
    }
    float xc0 = xb[3], xc1 = xb[4], xc2 = xb[5];

    // ---- block anti-phase stagger (one-time, ~512 cyc ~ half step) ----
    if ((bid ^ (bid >> 8)) & 1) {
        __builtin_amdgcn_s_sleep(8);
    }

    for (int t = 0; t < kT; ++t) {
        // ---- 3 MFMA: depth-3 hi/lo chain, C carries exact fp32 xp ----
        f32x4 a0 = MFMA16(Ah.v, Bh.v, xp, 0, 0, 0);
        a0 = MFMA16(Al.v, Bh.v, a0, 0, 0, 0);
        a0 = MFMA16(Ah.v, Bl.v, a0, 0, 0, 0);

        // ---- shadow work: prefetch x(t+2), XP(t+1) from held x(t+1) ----
        const int tn = (t + 2 < kT) ? t + 2 : kT - 1;
        const float xn0 = xb[tn * 3 + 0];
        const float xn1 = xb[tn * 3 + 1];
        const float xn2 = xb[tn * 3 + 2];
#pragma unroll
        for (int g = 0; g < 4; ++g)
            xp[g] = fmaf(xc0, xw[g][0],
                    fmaf(xc1, xw[g][1],
                    fmaf(xc2, xw[g][2], xbias[g])));

        // ---- gate math (scalar, 1 unit): acc[r] = gate r ----
        const float Ei = fast_exp2(a0[0]);
        const float Ef = fast_exp2(a0[1]);
        const float Eg = fast_exp2(a0[2]);
        const float Eo = fast_exp2(a0[3]);
        const float pf  = 1.0f + Ef;
        const float pi  = 1.0f + Ei;
        const float pg  = 1.0f + Eg;
        const float tig = pi * pg;
        const float den = tig * pf;
        const float num = fmaf(cst, tig, (1.0f - Eg) * pf);
        const float c   = num * fast_rcp(den);
        cst = c;
        float Ec = fast_exp2(c * (-2.0f * kL2E));
        Ec = fminf(Ec, 1e30f);
        const float od = (1.0f + Eo) * (1.0f + Ec);
        const float h  = (1.0f - Ec) * fast_rcp(od);

        // ---- pack hi/lo (RNE hi + exact residual) and store to LDS ----
        const unsigned short hi = bf_rne(h);
        const unsigned short lo = bf_rne(h - bf_tof(hi));

        const int buf = t & 1;
        lds_h[buf][0][n][u0] = hi;
        lds_h[buf][1][n][u0] = lo;

        __syncthreads();

        // ---- B frags for next step: units 8q..8q+7 of batch n ----
        Bh.q4 = *(const u32x4*)&lds_h[buf][0][n][8 * q];
        Bl.q4 = *(const u32x4*)&lds_h[buf][1][n][8 * q];

        xc0 = xn0; xc1 = xn1; xc2 = xn2;
    }

    // ---- epilogue (wave 0): h(511) is in lds buf 1 ----
    if (w == 0) {
        Frag Hh, Hl;
        Hh.q4 = *(const u32x4*)&lds_h[1][0][n][8 * q];
        Hl.q4 = *(const u32x4*)&lds_h[1][1][n][8 * q];
        float s0 = 0.f, s1 = 0.f;
#pragma unroll
        for (int j = 0; j < 8; ++j) {
            const float hv = bf_tof(Hh.u[j]) + bf_tof(Hl.u[j]);
            const int   u  = 8 * q + j;
            s0 = fmaf(hv, W_fc[u], s0);
            s1 = fmaf(hv, W_fc[32 + u], s1);
        }
        s0 += __shfl_xor(s0, 16, 64); s1 += __shfl_xor(s1, 16, 64);
        s0 += __shfl_xor(s0, 32, 64); s1 += __shfl_xor(s1, 32, 64);
        if (lane < 16) {
            out[(size_t)batch * 2 + 0] = s0 + b_fc[0];
            out[(size_t)batch * 2 + 1] = s1 + b_fc[1];
        }
    }
}

extern "C" void kernel_launch(void* const* d_in, const int* in_sizes, int n_in,
                              void* d_out, int out_size, void* d_ws, size_t ws_size,
                              hipStream_t stream) {
    const float* x    = (const float*)d_in[0];
    const float* W_ih = (const float*)d_in[1];
    const float* W_hh = (const float*)d_in[2];
    const float* b_ih = (const float*)d_in[3];
    const float* b_hh = (const float*)d_in[4];
    const float* W_fc = (const float*)d_in[5];
    const float* b_fc = (const float*)d_in[6];
    float* out = (float*)d_out;

    const int batch = in_sizes[0] / (kT * 3);   // 8192
    dim3 grid(batch / 16);                      // 512 blocks of 8 waves
    dim3 block(512);                            // -> 2 blocks/CU, 4 waves/SIMD
    hipLaunchKernelGGL(lstm_split8, grid, block, 0, stream,
                       x, W_ih, W_hh, b_ih, b_hh, W_fc, b_fc, out);
}